// Round 11
// baseline (391.653 us; speedup 1.0000x reference)
//
#include <hip/hip_runtime.h>
#include <math.h>

#define NN 100000
#define EE 3200000
#define ET 3300000   // EE + NN self loops
#define FIN 512
#define HDIM 64
#define NCLS 40
#define OST3 64      // padded layer-3 h row stride (shorts) -> one 128B line per row

// bucket sort params
#define NBUK 512
#define NPB 196          // nodes per bucket; buckets 0..510 used
#define NBUK_USED 511
#define EPB 4096
#define EPT 16
#define CAP 8192         // per-bucket slot capacity (mean 6458, sigma~80)
#define NCH 7            // src chunks (src>>14): 7 x 16384 covers 100000

#define G1TILES 782      // ceil(NN/128)
#define G1H 391          // half of gemm1 tiles per mixed phase
#define GBUK 806         // ceil(ET/EPB)

typedef __attribute__((ext_vector_type(8))) short frag_ab;
typedef __attribute__((ext_vector_type(4))) float frag_cd;

#define CVTPK(dst, a, b) asm("v_cvt_pk_bf16_f32 %0, %1, %2" : "=v"(dst) : "v"(a), "v"(b))

__device__ inline unsigned short f2bf(float f){
  union { float f; unsigned int u; } x; x.f = f;
  unsigned int u = x.u;
  unsigned int r = u + 0x7FFF + ((u >> 16) & 1);
  return (unsigned short)(r >> 16);
}
__device__ inline float bflo(unsigned u){
  union { unsigned u; float f; } x; x.u = u << 16; return x.f;
}
__device__ inline float bfhi(unsigned u){
  union { unsigned u; float f; } x; x.u = u & 0xFFFF0000u; return x.f;
}
__device__ inline float bf2f(unsigned short u){
  union { unsigned int u; float f; } x; x.u = ((unsigned int)u) << 16;
  return x.f;
}
// order-preserving float<->uint key for atomicMax (memset-0 < any real key)
__device__ inline unsigned fkey(float f){
  union { float f; unsigned u; } x; x.f = f;
  return (x.u >> 31) ? ~x.u : (x.u | 0x80000000u);
}
__device__ inline float funkey(unsigned k){
  union { unsigned u; float f; } x;
  x.u = (k & 0x80000000u) ? (k ^ 0x80000000u) : ~k;
  return x.f;
}

// ---------------- prep: weights -> bf16 transposed, scaled att vecs ----------------
__global__ void k_prep(const float* __restrict__ W1, const float* __restrict__ W2, const float* __restrict__ W3,
                       const float* __restrict__ as1, const float* __restrict__ ad1,
                       const float* __restrict__ as2, const float* __restrict__ ad2,
                       const float* __restrict__ as3, const float* __restrict__ ad3,
                       unsigned short* __restrict__ Wt1, unsigned short* __restrict__ Wt2,
                       unsigned short* __restrict__ Wt3, float* __restrict__ attv){
  int i = blockIdx.x*256 + threadIdx.x;
  if(i < 32768){
    int n = i >> 9, k = i & 511;
    Wt1[i] = f2bf(W1[k*HDIM + n]);
  } else if(i < 36864){
    int i2 = i - 32768; int n = i2 >> 6, k = i2 & 63;
    Wt2[i2] = f2bf(W2[k*HDIM + n]);
  } else if(i < 40960){
    int i3 = i - 36864; int n = i3 >> 6, k = i3 & 63;
    Wt3[i3] = (n < NCLS) ? f2bf(W3[k*NCLS + n]) : (unsigned short)0;
  } else if(i < 41312){
    int j = i - 40960;
    const float L2E = 1.4426950408889634f;
    float v;
    if(j < 64) v = as1[j]*L2E;
    else if(j < 128) v = ad1[j-64]*L2E;
    else if(j < 192) v = as2[j-128]*L2E;
    else if(j < 256) v = ad2[j-192]*L2E;
    else if(j < 304){ int q=j-256; v = (q<NCLS)? as3[q]*L2E : 0.f; }
    else { int q=j-304; v = (q<NCLS)? ad3[q]*L2E : 0.f; }
    attv[j] = v;
  }
}

// ---------------- fused attention-coefficient epilogues ----------------
template<int CT>
__device__ inline void att_epi8(const frag_cd (&acc)[2][CT], int rowbase, int fr, int kg,
                                const float* __restrict__ asv, const float* __restrict__ adv,
                                unsigned short* __restrict__ as_o, float* __restrict__ ad_o,
                                float (*gml)[8], int w, int M){
  float av[CT], dv[CT];
  #pragma unroll
  for(int j=0;j<CT;j++){ av[j]=asv[j*16+fr]; dv[j]=adv[j*16+fr]; }
  float mx[CT];
  #pragma unroll
  for(int j=0;j<CT;j++) mx[j] = -1e38f;
  #pragma unroll
  for(int i=0;i<2;i++){
    #pragma unroll
    for(int r=0;r<4;r++){
      int row = rowbase + i*16 + kg*4 + r;
      float ps[CT], pd[CT];
      #pragma unroll
      for(int j=0;j<CT;j++){ float v = acc[i][j][r]; ps[j]=v*av[j]; pd[j]=v*dv[j]; }
      #pragma unroll
      for(int mk=1; mk<8; mk<<=1){
        #pragma unroll
        for(int j=0;j<CT;j++){ ps[j]+=__shfl_xor(ps[j],mk); pd[j]+=__shfl_xor(pd[j],mk); }
      }
      if((fr&7)==0 && row < M){
        int half = fr>>3;
        uint2 s2;
        CVTPK(s2.x, ps[0], ps[1]);
        CVTPK(s2.y, ps[2], ps[3]);
        *(uint2*)&as_o[row*8 + half*4] = s2;
        float4 d4; d4.x=pd[0]; d4.y=pd[1]; d4.z=pd[2]; d4.w=pd[3];
        *(float4*)&ad_o[row*8 + half*4] = d4;
        #pragma unroll
        for(int j=0;j<CT;j++) mx[j] = fmaxf(mx[j], ps[j]);
      }
    }
  }
  #pragma unroll
  for(int j=0;j<CT;j++){
    mx[j] = fmaxf(mx[j], __shfl_xor(mx[j],16));
    mx[j] = fmaxf(mx[j], __shfl_xor(mx[j],32));
  }
  if(kg==0 && (fr&7)==0){
    int half = fr>>3;
    #pragma unroll
    for(int j=0;j<CT;j++) gml[w][half*4 + j] = mx[j];
  }
}

template<int CT>
__device__ inline void att_epi1(const frag_cd (&acc)[2][CT], int rowbase, int fr, int kg,
                                const float* __restrict__ asv, const float* __restrict__ adv,
                                float* __restrict__ as_o, float* __restrict__ ad_o,
                                float (*gml)[8], int w, int lane, int M){
  float av[CT], dv[CT];
  #pragma unroll
  for(int j=0;j<CT;j++){ av[j]=asv[j*16+fr]; dv[j]=adv[j*16+fr]; }
  float mx = -1e38f;
  #pragma unroll
  for(int i=0;i<2;i++){
    #pragma unroll
    for(int r=0;r<4;r++){
      int row = rowbase + i*16 + kg*4 + r;
      float ps=0.f, pd=0.f;
      #pragma unroll
      for(int j=0;j<CT;j++){ float v = acc[i][j][r]; ps += v*av[j]; pd += v*dv[j]; }
      #pragma unroll
      for(int mk=1; mk<16; mk<<=1){ ps+=__shfl_xor(ps,mk); pd+=__shfl_xor(pd,mk); }
      if(row < M){
        mx = fmaxf(mx, ps);
        if(fr==0){ as_o[row]=ps; ad_o[row]=pd; }
      }
    }
  }
  #pragma unroll
  for(int mk=1; mk<64; mk<<=1) mx = fmaxf(mx, __shfl_xor(mx, mk));
  if(lane==0) gml[w][0] = mx;
}

// ---------------- mixed kernel: gemm1 half-tiles + (bucket | bfinal) ----------------
#define BM 128
#define BK 32
#define LSTR 40
// PHASE 0: blocks [0,G1H) = gemm1 tiles [0,G1H); blocks [G1H, G1H+GBUK) = bucket
// PHASE 1: blocks [0,G1H) = gemm1 tiles [G1H, 782); blocks [G1H, G1H+511) = bfinal
template<int PHASE>
__global__ __launch_bounds__(256) void k_mix(const float* __restrict__ A, const unsigned short* __restrict__ Wt,
                                             const float* __restrict__ asv, const float* __restrict__ adv,
                                             unsigned short* __restrict__ Out,
                                             unsigned short* __restrict__ as_o, float* __restrict__ ad_o,
                                             unsigned* __restrict__ gmax,
                                             const int* __restrict__ src, const int* __restrict__ dst,
                                             int* __restrict__ bcur, int* __restrict__ pbuf,
                                             int* __restrict__ rp, int* __restrict__ col){
  __shared__ __attribute__((aligned(16))) unsigned short Al[2][BM*LSTR];
  __shared__ __attribute__((aligned(16))) unsigned short Bl[2][64*LSTR];
  __shared__ float gml[4][8];
  int t = threadIdx.x;

  if(blockIdx.x >= G1H){
    int* shi = (int*)&Al[0][0];
    if(PHASE == 0){
      // -------- bucket pass --------
      int bb = blockIdx.x - G1H;
      int* lcnt  = shi;
      int* lbase = shi + NBUK;
      for(int i=t;i<NBUK;i+=256) lcnt[i]=0;
      __syncthreads();
      int base = bb*EPB + t;
      int bk[EPT], rk[EPT], pk[EPT];
      #pragma unroll
      for(int j=0;j<EPT;j++){
        int e = base + j*256;
        bk[j] = -1;
        if(e < ET){
          int s, d;
          if(e < EE){ s = src[e]; d = dst[e]; } else { s = e - EE; d = s; }
          int b = d / NPB;
          bk[j] = b;
          pk[j] = s | ((d - b*NPB) << 17);
          rk[j] = atomicAdd(&lcnt[b], 1);
        }
      }
      __syncthreads();
      for(int i=t;i<NBUK;i+=256){
        int v = lcnt[i];
        lbase[i] = v ? atomicAdd(&bcur[i], v) : 0;
      }
      __syncthreads();
      #pragma unroll
      for(int j=0;j<EPT;j++){
        if(bk[j] >= 0){
          int pos = lbase[bk[j]] + rk[j];
          if(pos < CAP) pbuf[(size_t)bk[j]*CAP + pos] = pk[j];
        }
      }
    } else {
      // -------- bfinal pass: per-(node, src-chunk) counting -> col grouped by src chunk --------
      int b = blockIdx.x - G1H;
      int* red = shi;            // 256
      int* cnt = shi + 256;      // NPB*NCH = 1372
      int part = 0;
      for(int i=t; i<b; i+=256) part += bcur[i];
      red[t] = part;
      __syncthreads();
      for(int off=128; off; off>>=1){
        if(t < off) red[t] += red[t+off];
        __syncthreads();
      }
      int beg = red[0];
      int cntb = bcur[b];
      const int* pb = pbuf + (size_t)b*CAP;
      for(int i=t;i<NPB*NCH;i+=256) cnt[i]=0;
      __syncthreads();
      for(int i=t; i<cntb; i+=256){
        int v = pb[i];
        int dloc = v >> 17, s = v & 0x1FFFF;
        atomicAdd(&cnt[dloc*NCH + (s>>14)], 1);
      }
      __syncthreads();
      // exclusive scan over 1372 counters by wave 0 (22 per lane)
      if(t < 64){
        int vals[22]; int sum = 0;
        #pragma unroll
        for(int j=0;j<22;j++){ int idx = t*22+j; int v = (idx<NPB*NCH)?cnt[idx]:0; vals[j]=v; sum+=v; }
        int incl = sum;
        #pragma unroll
        for(int off=1; off<64; off<<=1){
          int x = __shfl_up(incl, off);
          if(t >= off) incl += x;
        }
        int run = incl - sum;
        #pragma unroll
        for(int j=0;j<22;j++){
          int idx = t*22+j;
          if(idx < NPB*NCH){ int v = vals[j]; cnt[idx] = run; run += v; }
        }
      }
      __syncthreads();
      int node0 = b*NPB;
      int nloc = NN - node0; if(nloc > NPB) nloc = NPB;
      for(int i=t;i<nloc;i+=256) rp[node0 + i] = beg + cnt[i*NCH];
      if(b == 0 && t == 0) rp[NN] = ET;
      __syncthreads();
      for(int i=t; i<cntb; i+=256){
        int v = pb[i];
        int s = v & 0x1FFFF;
        int dloc = v >> 17;
        int pos = atomicAdd(&cnt[dloc*NCH + (s>>14)], 1);
        col[beg + pos] = s;
      }
    }
    return;
  }

  // -------- gemm1 half --------
  int w = t >> 6, l = t & 63;
  int row0 = (blockIdx.x + PHASE*G1H) * BM;
  int M = NN;

  int srow = t >> 1;
  int shalf = t & 1;
  int bn = t >> 2;
  int bseg = t & 3;
  int fr = l & 15, kg = l >> 4;

  frag_cd acc[2][4];
  #pragma unroll
  for(int i=0;i<2;i++)
    #pragma unroll
    for(int j=0;j<4;j++) acc[i][j] = (frag_cd){0.f,0.f,0.f,0.f};

  int rg = row0 + srow; if(rg >= M) rg = M-1;
  const float* aprow = &A[(size_t)rg*FIN + shalf*16];

  #define STAGE(buf, kc) do { \
    const float* ap = aprow + (kc); \
    float4 v0 = *(const float4*)(ap); \
    float4 v1 = *(const float4*)(ap+4); \
    float4 v2 = *(const float4*)(ap+8); \
    float4 v3 = *(const float4*)(ap+12); \
    uint4 pa, pb; \
    CVTPK(pa.x, v0.x, v0.y); CVTPK(pa.y, v0.z, v0.w); \
    CVTPK(pa.z, v1.x, v1.y); CVTPK(pa.w, v1.z, v1.w); \
    CVTPK(pb.x, v2.x, v2.y); CVTPK(pb.y, v2.z, v2.w); \
    CVTPK(pb.z, v3.x, v3.y); CVTPK(pb.w, v3.z, v3.w); \
    *(uint4*)&Al[buf][srow*LSTR + shalf*16] = pa; \
    *(uint4*)&Al[buf][srow*LSTR + shalf*16 + 8] = pb; \
    *(uint4*)&Bl[buf][bn*LSTR + bseg*8] = *(const uint4*)&Wt[bn*FIN + (kc) + bseg*8]; \
  } while(0)

  STAGE(0, 0);
  __syncthreads();

  #pragma unroll 1
  for(int step = 0; step < FIN/BK; ++step){
    int buf = step & 1;
    if(step + 1 < FIN/BK) STAGE(buf^1, (step+1)*BK);
    frag_ab af[2], bfr[4];
    #pragma unroll
    for(int i=0;i<2;i++) af[i] = *(const frag_ab*)&Al[buf][(w*32 + i*16 + fr)*LSTR + kg*8];
    #pragma unroll
    for(int j=0;j<4;j++) bfr[j] = *(const frag_ab*)&Bl[buf][(j*16 + fr)*LSTR + kg*8];
    #pragma unroll
    for(int i=0;i<2;i++)
      #pragma unroll
      for(int j=0;j<4;j++)
        acc[i][j] = __builtin_amdgcn_mfma_f32_16x16x32_bf16(af[i], bfr[j], acc[i][j], 0, 0, 0);
    __syncthreads();
  }

  #pragma unroll
  for(int i=0;i<2;i++){
    int crow = row0 + w*32 + i*16 + kg*4;
    #pragma unroll
    for(int j=0;j<4;j++){
      int ccol = j*16 + fr;
      #pragma unroll
      for(int r=0;r<4;r++){
        if(crow + r < M) Out[(size_t)(crow+r)*HDIM + ccol] = f2bf(acc[i][j][r]);
      }
    }
  }
  att_epi8(acc, row0 + w*32, fr, kg, asv, adv, as_o, ad_o, gml, w, M);
  __syncthreads();
  if(t < 8){
    float v = fmaxf(fmaxf(gml[0][t], gml[1][t]), fmaxf(gml[2][t], gml[3][t]));
    atomicMax(&gmax[t], fkey(v));
  }
  #undef STAGE
}

// ---------------- bf16 MFMA GEMM (layers 2,3) with fused att ----------------
template<int K, int C, int OST, int HEADS>
__global__ __launch_bounds__(256) void k_gemmb(const unsigned short* __restrict__ A,
                                               const unsigned short* __restrict__ Wt,
                                               const float* __restrict__ asv, const float* __restrict__ adv,
                                               unsigned short* __restrict__ Out,
                                               void* __restrict__ as_o, float* __restrict__ ad_o,
                                               unsigned* __restrict__ gmax, int M){
  constexpr int CT = (C + 15)/16;
  __shared__ __attribute__((aligned(16))) unsigned short Al[2][BM*LSTR];
  __shared__ __attribute__((aligned(16))) unsigned short Bl[2][64*LSTR];
  __shared__ float gml[4][8];
  int t = threadIdx.x;
  int w = t >> 6, l = t & 63;
  int row0 = blockIdx.x * BM;

  int srow = t >> 1;
  int shalf = t & 1;
  int bn = t >> 2;
  int bseg = t & 3;
  int fr = l & 15, kg = l >> 4;

  frag_cd acc[2][CT];
  #pragma unroll
  for(int i=0;i<2;i++)
    #pragma unroll
    for(int j=0;j<CT;j++) acc[i][j] = (frag_cd){0.f,0.f,0.f,0.f};

  int rg = row0 + srow; if(rg >= M) rg = M-1;
  const unsigned short* aprow = &A[(size_t)rg*K + shalf*16];

  #define STAGEB(buf, kc) do { \
    *(uint4*)&Al[buf][srow*LSTR + shalf*16]     = *(const uint4*)(aprow + (kc)); \
    *(uint4*)&Al[buf][srow*LSTR + shalf*16 + 8] = *(const uint4*)(aprow + (kc) + 8); \
    *(uint4*)&Bl[buf][bn*LSTR + bseg*8] = *(const uint4*)&Wt[bn*K + (kc) + bseg*8]; \
  } while(0)

  STAGEB(0, 0);
  __syncthreads();

  #pragma unroll 1
  for(int step = 0; step < K/BK; ++step){
    int buf = step & 1;
    if(step + 1 < K/BK) STAGEB(buf^1, (step+1)*BK);
    frag_ab af[2], bfr[CT];
    #pragma unroll
    for(int i=0;i<2;i++) af[i] = *(const frag_ab*)&Al[buf][(w*32 + i*16 + fr)*LSTR + kg*8];
    #pragma unroll
    for(int j=0;j<CT;j++) bfr[j] = *(const frag_ab*)&Bl[buf][(j*16 + fr)*LSTR + kg*8];
    #pragma unroll
    for(int i=0;i<2;i++)
      #pragma unroll
      for(int j=0;j<CT;j++)
        acc[i][j] = __builtin_amdgcn_mfma_f32_16x16x32_bf16(af[i], bfr[j], acc[i][j], 0, 0, 0);
    __syncthreads();
  }

  #pragma unroll
  for(int i=0;i<2;i++){
    int crow = row0 + w*32 + i*16 + kg*4;
    #pragma unroll
    for(int j=0;j<CT;j++){
      int ccol = j*16 + fr;
      if(ccol >= C) continue;
      #pragma unroll
      for(int r=0;r<4;r++){
        if(crow + r < M) Out[(size_t)(crow+r)*OST + ccol] = f2bf(acc[i][j][r]);
      }
    }
  }
  if(HEADS == 8){
    att_epi8(acc, row0 + w*32, fr, kg, asv, adv, (unsigned short*)as_o, ad_o, gml, w, M);
    __syncthreads();
    if(t < 8){
      float v = fmaxf(fmaxf(gml[0][t], gml[1][t]), fmaxf(gml[2][t], gml[3][t]));
      atomicMax(&gmax[t], fkey(v));
    }
  } else {
    att_epi1(acc, row0 + w*32, fr, kg, asv, adv, (float*)as_o, ad_o, gml, w, l, M);
    __syncthreads();
    if(t == 0){
      float v = fmaxf(fmaxf(gml[0][0], gml[1][0]), fmaxf(gml[2][0], gml[3][0]));
      atomicMax(&gmax[0], fkey(v));
    }
  }
  #undef STAGEB
}

// ---------------- aggregation, HEADS=8: fixed-max softmax, 8 lanes/edge ----------------
template<bool DO_ELU>
__global__ __launch_bounds__(256) void k_agg8(const unsigned short* __restrict__ hbf, const int* __restrict__ rp,
                      const int* __restrict__ col,
                      const unsigned short* __restrict__ asb, const float* __restrict__ ad_,
                      const unsigned* __restrict__ gmax,
                      const float* __restrict__ bias, unsigned short* __restrict__ out){
  int gid = blockIdx.x*256 + threadIdx.x;
  int node = gid >> 6, lane = gid & 63;
  if(node >= NN) return;
  int el = lane >> 3;
  int fl = lane & 7;
  int px = ((fl&1)<<2) | (fl>>1);          // storage position of head fl
  int beg = rp[node], end = rp[node+1];
  int deg = end - beg;
  float adn = ad_[node*8 + px];
  float M = funkey(gmax[px]) + adn;
  M = fmaxf(M, 0.2f*M);                    // leaky(gmax+ad) >= all edge logits
  float s = 0.f;
  float a[8] = {0.f,0.f,0.f,0.f,0.f,0.f,0.f,0.f};

  for(int base = 0; base < deg; base += 64){
    int cnt = deg - base; if(cnt > 64) cnt = 64;
    int idx = 0;
    if(lane < cnt) idx = col[beg + base + lane];
    int jf = cnt & ~7;
    int j = 0;
    for(; j < jf; j += 8){
      int sn = __shfl(idx, j + el);
      float ea = bf2f(asb[sn*8 + px]);
      uint4 h = *(const uint4*)&hbf[(size_t)sn*HDIM + fl*8];
      float e = ea + adn; e = fmaxf(e, 0.2f*e);
      float p = exp2f(e - M);
      s += p;
      a[0] = fmaf(p, bflo(h.x), a[0]); a[1] = fmaf(p, bfhi(h.x), a[1]);
      a[2] = fmaf(p, bflo(h.y), a[2]); a[3] = fmaf(p, bfhi(h.y), a[3]);
      a[4] = fmaf(p, bflo(h.z), a[4]); a[5] = fmaf(p, bfhi(h.z), a[5]);
      a[6] = fmaf(p, bflo(h.w), a[6]); a[7] = fmaf(p, bfhi(h.w), a[7]);
    }
    if(j < cnt){
      int sn = __shfl(idx, j + el);
      float ea = bf2f(asb[sn*8 + px]);
      uint4 h = *(const uint4*)&hbf[(size_t)sn*HDIM + fl*8];
      float e = ea + adn; e = fmaxf(e, 0.2f*e);
      float p = (j + el < cnt) ? exp2f(e - M) : 0.f;
      s += p;
      a[0] = fmaf(p, bflo(h.x), a[0]); a[1] = fmaf(p, bfhi(h.x), a[1]);
      a[2] = fmaf(p, bflo(h.y), a[2]); a[3] = fmaf(p, bfhi(h.y), a[3]);
      a[4] = fmaf(p, bflo(h.z), a[4]); a[5] = fmaf(p, bfhi(h.z), a[5]);
      a[6] = fmaf(p, bflo(h.w), a[6]); a[7] = fmaf(p, bfhi(h.w), a[7]);
    }
  }

  #pragma unroll
  for(int wd=8; wd<=32; wd<<=1){
    s += __shfl_xor(s, wd);
    #pragma unroll
    for(int i=0;i<8;i++) a[i] += __shfl_xor(a[i], wd);
  }

  if(el == 0){
    float inv = 1.f/s;
    float4 b0 = *(const float4*)&bias[fl*8];
    float4 b1 = *(const float4*)&bias[fl*8 + 4];
    float o[8];
    o[0]=a[0]*inv+b0.x; o[1]=a[1]*inv+b0.y; o[2]=a[2]*inv+b0.z; o[3]=a[3]*inv+b0.w;
    o[4]=a[4]*inv+b1.x; o[5]=a[5]*inv+b1.y; o[6]=a[6]*inv+b1.z; o[7]=a[7]*inv+b1.w;
    if(DO_ELU){
      #pragma unroll
      for(int i=0;i<8;i++) o[i] = (o[i] > 0.f) ? o[i] : expm1f(o[i]);
    }
    uint4 pk;
    CVTPK(pk.x, o[0], o[1]); CVTPK(pk.y, o[2], o[3]);
    CVTPK(pk.z, o[4], o[5]); CVTPK(pk.w, o[6], o[7]);
    *(uint4*)&out[(size_t)node*HDIM + fl*8] = pk;
  }
}

// ---------------- aggregation, HEADS=1 (layer 3, padded 64-short rows) + log-softmax ----------------
__global__ __launch_bounds__(256) void k_agg1(const unsigned short* __restrict__ hbf, const int* __restrict__ rp,
                      const int* __restrict__ col,
                      const float* __restrict__ as_, const float* __restrict__ ad_,
                      const unsigned* __restrict__ gmax,
                      const float* __restrict__ bias, float* __restrict__ out){
  int gid = blockIdx.x*256 + threadIdx.x;
  int node = gid >> 6, lane = gid & 63;
  if(node >= NN) return;
  int el = lane >> 3;
  int fl = lane & 7;
  bool act = fl < 5;                      // 5*8 = 40 features
  int f0 = act ? fl*8 : 0;
  int beg = rp[node], end = rp[node+1];
  int deg = end - beg;
  float adn = ad_[node];
  float M = funkey(gmax[0]) + adn;
  M = fmaxf(M, 0.2f*M);
  float s = 0.f;
  float a[8] = {0.f,0.f,0.f,0.f,0.f,0.f,0.f,0.f};

  for(int base = 0; base < deg; base += 64){
    int cnt = deg - base; if(cnt > 64) cnt = 64;
    int idx = 0;
    if(lane < cnt) idx = col[beg + base + lane];
    for(int j = 0; j < cnt; j += 8){
      int sn = __shfl(idx, j + el);
      float ea = as_[sn];
      uint4 h = *(const uint4*)&hbf[(size_t)sn*OST3 + f0];
      float e = ea + adn; e = fmaxf(e, 0.2f*e);
      float p = (j + el < cnt) ? exp2f(e - M) : 0.f;
      s += p;
      a[0] = fmaf(p, bflo(h.x), a[0]); a[1] = fmaf(p, bfhi(h.x), a[1]);
      a[2] = fmaf(p, bflo(h.y), a[2]); a[3] = fmaf(p, bfhi(h.y), a[3]);
      a[4] = fmaf(p, bflo(h.z), a[4]); a[5] = fmaf(p, bfhi(h.z), a[5]);
      a[6] = fmaf(p, bflo(h.w), a[6]); a[7] = fmaf(p, bfhi(h.w), a[7]);
    }
  }

  #pragma unroll
  for(int wd=8; wd<=32; wd<<=1){
    s += __shfl_xor(s, wd);
    #pragma unroll
    for(int i=0;i<8;i++) a[i] += __shfl_xor(a[i], wd);
  }

  float inv = 1.f/s;
  float o[8];
  #pragma unroll
  for(int i=0;i<8;i++) o[i] = a[i]*inv + (act ? bias[f0+i] : 0.f);

  float vmax = act ? fmaxf(fmaxf(fmaxf(o[0],o[1]),fmaxf(o[2],o[3])),
                           fmaxf(fmaxf(o[4],o[5]),fmaxf(o[6],o[7]))) : -INFINITY;
  #pragma unroll
  for(int wd=1; wd<8; wd<<=1) vmax = fmaxf(vmax, __shfl_xor(vmax, wd));
  float ex = 0.f;
  if(act){
    #pragma unroll
    for(int i=0;i<8;i++) ex += expf(o[i] - vmax);
  }
  #pragma unroll
  for(int wd=1; wd<8; wd<<=1) ex += __shfl_xor(ex, wd);
  float lg = logf(ex);
  if(el == 0 && act){
    float4 r0, r1;
    r0.x=o[0]-vmax-lg; r0.y=o[1]-vmax-lg; r0.z=o[2]-vmax-lg; r0.w=o[3]-vmax-lg;
    r1.x=o[4]-vmax-lg; r1.y=o[5]-vmax-lg; r1.z=o[6]-vmax-lg; r1.w=o[7]-vmax-lg;
    *(float4*)&out[(size_t)node*NCLS + f0]     = r0;
    *(float4*)&out[(size_t)node*NCLS + f0 + 4] = r1;
  }
}

// ---------------- launch ----------------
static inline size_t alignup(size_t x){ return (x + 255) & ~(size_t)255; }

extern "C" void kernel_launch(void* const* d_in, const int* in_sizes, int n_in,
                              void* d_out, int out_size, void* d_ws, size_t ws_size,
                              hipStream_t stream){
  const float* x      = (const float*)d_in[0];
  const int*   ei     = (const int*)d_in[1];
  const float* W1     = (const float*)d_in[2];
  const float* asrc1  = (const float*)d_in[3];
  const float* adst1  = (const float*)d_in[4];
  const float* b1     = (const float*)d_in[5];
  const float* W2     = (const float*)d_in[6];
  const float* asrc2  = (const float*)d_in[7];
  const float* adst2  = (const float*)d_in[8];
  const float* b2     = (const float*)d_in[9];
  const float* W3     = (const float*)d_in[10];
  const float* asrc3  = (const float*)d_in[11];
  const float* adst3  = (const float*)d_in[12];
  const float* b3     = (const float*)d_in[13];
  const int* src = ei;
  const int* dst = ei + EE;

  char* w = (char*)d_ws;
  int* rp     = (int*)w;              w += alignup((size_t)(NN+1)*4);
  int* bcur   = (int*)w;              w += alignup((size_t)NBUK*4);   // 2048B
  unsigned* gmax = (unsigned*)w;      w += alignup(32*4);             // adjacent to bcur
  unsigned short* Wt1 = (unsigned short*)w; w += alignup((size_t)64*FIN*2);
  unsigned short* Wt2 = (unsigned short*)w; w += alignup((size_t)64*HDIM*2);
  unsigned short* Wt3 = (unsigned short*)w; w += alignup((size_t)64*HDIM*2);
  float* attv = (float*)w;            w += alignup((size_t)352*4);
  int* col    = (int*)w;              w += alignup((size_t)ET*4);
  int* pbuf   = (int*)w;              w += alignup((size_t)NBUK*CAP*4);
  unsigned short* hAb = (unsigned short*)w; w += alignup((size_t)NN*HDIM*2 + 256);
  unsigned short* hBb = (unsigned short*)w; w += alignup((size_t)NN*HDIM*2 + 256);
  unsigned short* hCb = (unsigned short*)w; w += alignup((size_t)NN*OST3*2 + 256);
  unsigned short* asb = (unsigned short*)w; w += alignup((size_t)NN*8*2 + 256);
  float* as3  = (float*)w;            w += alignup((size_t)NN*4);
  float* adA  = (float*)w;            w += alignup((size_t)NN*8*4);

  dim3 blk(256);
  int gWav  = (NN*64 + 255)/256;
  int gG1   = (NN + BM - 1)/BM;   // 782

  // zero bcur + gmax in one memset (they are adjacent: 2048 + 128 bytes)
  hipMemsetAsync(bcur, 0, 2048 + 128, stream);
  // prep (weights + scaled att vecs)
  k_prep<<<(41312 + 255)/256, blk, 0, stream>>>(W1, W2, W3, asrc1, adst1, asrc2, adst2, asrc3, adst3,
                                                Wt1, Wt2, Wt3, attv);
  // phase 0: gemm1 first half || bucket ; phase 1: gemm1 second half || bfinal
  k_mix<0><<<G1H + GBUK, blk, 0, stream>>>(x, Wt1, attv + 0, attv + 64, hAb, asb, adA, gmax + 0,
                                           src, dst, bcur, pbuf, rp, col);
  k_mix<1><<<G1H + NBUK_USED, blk, 0, stream>>>(x, Wt1, attv + 0, attv + 64, hAb, asb, adA, gmax + 0,
                                                src, dst, bcur, pbuf, rp, col);

  // layer 1 aggregation
  k_agg8<true><<<gWav, blk, 0, stream>>>(hAb, rp, col, asb, adA, gmax + 0, b1, hBb);

  // layer 2
  k_gemmb<HDIM, HDIM, HDIM, 8><<<gG1, blk, 0, stream>>>(hBb, Wt2, attv + 128, attv + 192, hAb, asb, adA, gmax + 8, NN);
  k_agg8<true><<<gWav, blk, 0, stream>>>(hAb, rp, col, asb, adA, gmax + 8, b2, hBb);

  // layer 3 (padded 64-short h rows)
  k_gemmb<HDIM, NCLS, OST3, 1><<<gG1, blk, 0, stream>>>(hBb, Wt3, attv + 256, attv + 304, hCb, as3, adA, gmax + 16, NN);
  k_agg1<<<gWav, blk, 0, stream>>>(hCb, rp, col, as3, adA, gmax + 16, b3, (float*)d_out);
}

// Round 12
// 386.773 us; speedup vs baseline: 1.0126x; 1.0126x over previous
//
#include <hip/hip_runtime.h>
#include <math.h>

#define NN 100000
#define EE 3200000
#define ET 3300000   // EE + NN self loops
#define FIN 512
#define HDIM 64
#define NCLS 40
#define OST3 64      // padded layer-3 h row stride (shorts) -> one 128B line per row

// bucket sort params
#define NBUK 512
#define NPB 196          // nodes per bucket; buckets 0..510 used
#define NBUK_USED 511
#define EPB 4096
#define EPT 16
#define CAP 8192         // per-bucket slot capacity (mean 6458, sigma~80)
#define NCH 7            // src chunks (src>>14)

#define G1TILES 782      // ceil(NN/128)
#define G1H 391          // half of gemm1 tiles per mixed phase
#define GBUK 806         // ceil(ET/EPB)

typedef __attribute__((ext_vector_type(8))) short frag_ab;
typedef __attribute__((ext_vector_type(4))) float frag_cd;
typedef __attribute__((ext_vector_type(2))) float float2v;

#define CVTPK(dst, a, b) asm("v_cvt_pk_bf16_f32 %0, %1, %2" : "=v"(dst) : "v"(a), "v"(b))

__device__ inline unsigned short f2bf(float f){
  union { float f; unsigned int u; } x; x.f = f;
  unsigned int u = x.u;
  unsigned int r = u + 0x7FFF + ((u >> 16) & 1);
  return (unsigned short)(r >> 16);
}
__device__ inline unsigned char f2fp8(float v){
  int p = __builtin_amdgcn_cvt_pk_fp8_f32(v, v, 0, false);
  return (unsigned char)p;
}
__device__ inline float bflo(unsigned u){
  union { unsigned u; float f; } x; x.u = u << 16; return x.f;
}
__device__ inline float bfhi(unsigned u){
  union { unsigned u; float f; } x; x.u = u & 0xFFFF0000u; return x.f;
}
__device__ inline float bf2f(unsigned short u){
  union { unsigned int u; float f; } x; x.u = ((unsigned int)u) << 16;
  return x.f;
}
// order-preserving float<->uint key for atomicMax (memset-0 < any real key)
__device__ inline unsigned fkey(float f){
  union { float f; unsigned u; } x; x.f = f;
  return (x.u >> 31) ? ~x.u : (x.u | 0x80000000u);
}
__device__ inline float funkey(unsigned k){
  union { unsigned u; float f; } x;
  x.u = (k & 0x80000000u) ? (k ^ 0x80000000u) : ~k;
  return x.f;
}

// ---------------- prep: weights -> bf16 transposed, scaled att vecs ----------------
__global__ void k_prep(const float* __restrict__ W1, const float* __restrict__ W2, const float* __restrict__ W3,
                       const float* __restrict__ as1, const float* __restrict__ ad1,
                       const float* __restrict__ as2, const float* __restrict__ ad2,
                       const float* __restrict__ as3, const float* __restrict__ ad3,
                       unsigned short* __restrict__ Wt1, unsigned short* __restrict__ Wt2,
                       unsigned short* __restrict__ Wt3, float* __restrict__ attv){
  int i = blockIdx.x*256 + threadIdx.x;
  if(i < 32768){
    int n = i >> 9, k = i & 511;
    Wt1[i] = f2bf(W1[k*HDIM + n]);
  } else if(i < 36864){
    int i2 = i - 32768; int n = i2 >> 6, k = i2 & 63;
    Wt2[i2] = f2bf(W2[k*HDIM + n]);
  } else if(i < 40960){
    int i3 = i - 36864; int n = i3 >> 6, k = i3 & 63;
    Wt3[i3] = (n < NCLS) ? f2bf(W3[k*NCLS + n]) : (unsigned short)0;
  } else if(i < 41312){
    int j = i - 40960;
    const float L2E = 1.4426950408889634f;
    float v;
    if(j < 64) v = as1[j]*L2E;
    else if(j < 128) v = ad1[j-64]*L2E;
    else if(j < 192) v = as2[j-128]*L2E;
    else if(j < 256) v = ad2[j-192]*L2E;
    else if(j < 304){ int q=j-256; v = (q<NCLS)? as3[q]*L2E : 0.f; }
    else { int q=j-304; v = (q<NCLS)? ad3[q]*L2E : 0.f; }
    attv[j] = v;
  }
}

// ---------------- fused attention-coefficient epilogues ----------------
template<int CT>
__device__ inline void att_epi8(const frag_cd (&acc)[2][CT], int rowbase, int fr, int kg,
                                const float* __restrict__ asv, const float* __restrict__ adv,
                                unsigned short* __restrict__ as_o, float* __restrict__ ad_o,
                                float (*gml)[8], int w, int M){
  float av[CT], dv[CT];
  #pragma unroll
  for(int j=0;j<CT;j++){ av[j]=asv[j*16+fr]; dv[j]=adv[j*16+fr]; }
  float mx[CT];
  #pragma unroll
  for(int j=0;j<CT;j++) mx[j] = -1e38f;
  #pragma unroll
  for(int i=0;i<2;i++){
    #pragma unroll
    for(int r=0;r<4;r++){
      int row = rowbase + i*16 + kg*4 + r;
      float ps[CT], pd[CT];
      #pragma unroll
      for(int j=0;j<CT;j++){ float v = acc[i][j][r]; ps[j]=v*av[j]; pd[j]=v*dv[j]; }
      #pragma unroll
      for(int mk=1; mk<8; mk<<=1){
        #pragma unroll
        for(int j=0;j<CT;j++){ ps[j]+=__shfl_xor(ps[j],mk); pd[j]+=__shfl_xor(pd[j],mk); }
      }
      if((fr&7)==0 && row < M){
        int half = fr>>3;
        uint2 s2;
        CVTPK(s2.x, ps[0], ps[1]);
        CVTPK(s2.y, ps[2], ps[3]);
        *(uint2*)&as_o[row*8 + half*4] = s2;
        float4 d4; d4.x=pd[0]; d4.y=pd[1]; d4.z=pd[2]; d4.w=pd[3];
        *(float4*)&ad_o[row*8 + half*4] = d4;
        #pragma unroll
        for(int j=0;j<CT;j++) mx[j] = fmaxf(mx[j], ps[j]);
      }
    }
  }
  #pragma unroll
  for(int j=0;j<CT;j++){
    mx[j] = fmaxf(mx[j], __shfl_xor(mx[j],16));
    mx[j] = fmaxf(mx[j], __shfl_xor(mx[j],32));
  }
  if(kg==0 && (fr&7)==0){
    int half = fr>>3;
    #pragma unroll
    for(int j=0;j<CT;j++) gml[w][half*4 + j] = mx[j];
  }
}

template<int CT>
__device__ inline void att_epi1(const frag_cd (&acc)[2][CT], int rowbase, int fr, int kg,
                                const float* __restrict__ asv, const float* __restrict__ adv,
                                float* __restrict__ as_o, float* __restrict__ ad_o,
                                float (*gml)[8], int w, int lane, int M){
  float av[CT], dv[CT];
  #pragma unroll
  for(int j=0;j<CT;j++){ av[j]=asv[j*16+fr]; dv[j]=adv[j*16+fr]; }
  float mx = -1e38f;
  #pragma unroll
  for(int i=0;i<2;i++){
    #pragma unroll
    for(int r=0;r<4;r++){
      int row = rowbase + i*16 + kg*4 + r;
      float ps=0.f, pd=0.f;
      #pragma unroll
      for(int j=0;j<CT;j++){ float v = acc[i][j][r]; ps += v*av[j]; pd += v*dv[j]; }
      #pragma unroll
      for(int mk=1; mk<16; mk<<=1){ ps+=__shfl_xor(ps,mk); pd+=__shfl_xor(pd,mk); }
      if(row < M){
        mx = fmaxf(mx, ps);
        if(fr==0){ as_o[row]=ps; ad_o[row]=pd; }
      }
    }
  }
  #pragma unroll
  for(int mk=1; mk<64; mk<<=1) mx = fmaxf(mx, __shfl_xor(mx, mk));
  if(lane==0) gml[w][0] = mx;
}

// ---------------- mixed kernel: gemm1 half-tiles + (bucket | bfinal) ----------------
#define BM 128
#define BK 32
#define LSTR 40
template<int PHASE>
__global__ __launch_bounds__(256) void k_mix(const float* __restrict__ A, const unsigned short* __restrict__ Wt,
                                             const float* __restrict__ asv, const float* __restrict__ adv,
                                             unsigned char* __restrict__ Out8,
                                             unsigned short* __restrict__ as_o, float* __restrict__ ad_o,
                                             unsigned* __restrict__ gmax,
                                             const int* __restrict__ src, const int* __restrict__ dst,
                                             int* __restrict__ bcur, int* __restrict__ pbuf,
                                             int* __restrict__ rp, int* __restrict__ col){
  __shared__ __attribute__((aligned(16))) unsigned short Al[2][BM*LSTR];
  __shared__ __attribute__((aligned(16))) unsigned short Bl[2][64*LSTR];
  __shared__ float gml[4][8];
  int t = threadIdx.x;

  if(blockIdx.x >= G1H){
    int* shi = (int*)&Al[0][0];
    if(PHASE == 0){
      // -------- bucket pass --------
      int bb = blockIdx.x - G1H;
      int* lcnt  = shi;
      int* lbase = shi + NBUK;
      for(int i=t;i<NBUK;i+=256) lcnt[i]=0;
      __syncthreads();
      int base = bb*EPB + t;
      int bk[EPT], rk[EPT], pk[EPT];
      #pragma unroll
      for(int j=0;j<EPT;j++){
        int e = base + j*256;
        bk[j] = -1;
        if(e < ET){
          int s, d;
          if(e < EE){ s = src[e]; d = dst[e]; } else { s = e - EE; d = s; }
          int b = d / NPB;
          bk[j] = b;
          pk[j] = s | ((d - b*NPB) << 17);
          rk[j] = atomicAdd(&lcnt[b], 1);
        }
      }
      __syncthreads();
      for(int i=t;i<NBUK;i+=256){
        int v = lcnt[i];
        lbase[i] = v ? atomicAdd(&bcur[i], v) : 0;
      }
      __syncthreads();
      #pragma unroll
      for(int j=0;j<EPT;j++){
        if(bk[j] >= 0){
          int pos = lbase[bk[j]] + rk[j];
          if(pos < CAP) pbuf[(size_t)bk[j]*CAP + pos] = pk[j];
        }
      }
    } else {
      // -------- bfinal pass: per-(node, src-chunk) counting --------
      int b = blockIdx.x - G1H;
      int* red = shi;            // 256
      int* cnt = shi + 256;      // NPB*NCH = 1372
      int part = 0;
      for(int i=t; i<b; i+=256) part += bcur[i];
      red[t] = part;
      __syncthreads();
      for(int off=128; off; off>>=1){
        if(t < off) red[t] += red[t+off];
        __syncthreads();
      }
      int beg = red[0];
      int cntb = bcur[b];
      const int* pb = pbuf + (size_t)b*CAP;
      for(int i=t;i<NPB*NCH;i+=256) cnt[i]=0;
      __syncthreads();
      for(int i=t; i<cntb; i+=256){
        int v = pb[i];
        int dloc = v >> 17, s = v & 0x1FFFF;
        atomicAdd(&cnt[dloc*NCH + (s>>14)], 1);
      }
      __syncthreads();
      if(t < 64){
        int vals[22]; int sum = 0;
        #pragma unroll
        for(int j=0;j<22;j++){ int idx = t*22+j; int v = (idx<NPB*NCH)?cnt[idx]:0; vals[j]=v; sum+=v; }
        int incl = sum;
        #pragma unroll
        for(int off=1; off<64; off<<=1){
          int x = __shfl_up(incl, off);
          if(t >= off) incl += x;
        }
        int run = incl - sum;
        #pragma unroll
        for(int j=0;j<22;j++){
          int idx = t*22+j;
          if(idx < NPB*NCH){ int v = vals[j]; cnt[idx] = run; run += v; }
        }
      }
      __syncthreads();
      int node0 = b*NPB;
      int nloc = NN - node0; if(nloc > NPB) nloc = NPB;
      for(int i=t;i<nloc;i+=256) rp[node0 + i] = beg + cnt[i*NCH];
      if(b == 0 && t == 0) rp[NN] = ET;
      __syncthreads();
      for(int i=t; i<cntb; i+=256){
        int v = pb[i];
        int s = v & 0x1FFFF;
        int dloc = v >> 17;
        int pos = atomicAdd(&cnt[dloc*NCH + (s>>14)], 1);
        col[beg + pos] = s;
      }
    }
    return;
  }

  // -------- gemm1 half --------
  int w = t >> 6, l = t & 63;
  int row0 = (blockIdx.x + PHASE*G1H) * BM;
  int M = NN;

  int srow = t >> 1;
  int shalf = t & 1;
  int bn = t >> 2;
  int bseg = t & 3;
  int fr = l & 15, kg = l >> 4;

  frag_cd acc[2][4];
  #pragma unroll
  for(int i=0;i<2;i++)
    #pragma unroll
    for(int j=0;j<4;j++) acc[i][j] = (frag_cd){0.f,0.f,0.f,0.f};

  int rg = row0 + srow; if(rg >= M) rg = M-1;
  const float* aprow = &A[(size_t)rg*FIN + shalf*16];

  #define STAGE(buf, kc) do { \
    const float* ap = aprow + (kc); \
    float4 v0 = *(const float4*)(ap); \
    float4 v1 = *(const float4*)(ap+4); \
    float4 v2 = *(const float4*)(ap+8); \
    float4 v3 = *(const float4*)(ap+12); \
    uint4 pa, pb; \
    CVTPK(pa.x, v0.x, v0.y); CVTPK(pa.y, v0.z, v0.w); \
    CVTPK(pa.z, v1.x, v1.y); CVTPK(pa.w, v1.z, v1.w); \
    CVTPK(pb.x, v2.x, v2.y); CVTPK(pb.y, v2.z, v2.w); \
    CVTPK(pb.z, v3.x, v3.y); CVTPK(pb.w, v3.z, v3.w); \
    *(uint4*)&Al[buf][srow*LSTR + shalf*16] = pa; \
    *(uint4*)&Al[buf][srow*LSTR + shalf*16 + 8] = pb; \
    *(uint4*)&Bl[buf][bn*LSTR + bseg*8] = *(const uint4*)&Wt[bn*FIN + (kc) + bseg*8]; \
  } while(0)

  STAGE(0, 0);
  __syncthreads();

  #pragma unroll 1
  for(int step = 0; step < FIN/BK; ++step){
    int buf = step & 1;
    if(step + 1 < FIN/BK) STAGE(buf^1, (step+1)*BK);
    frag_ab af[2], bfr[4];
    #pragma unroll
    for(int i=0;i<2;i++) af[i] = *(const frag_ab*)&Al[buf][(w*32 + i*16 + fr)*LSTR + kg*8];
    #pragma unroll
    for(int j=0;j<4;j++) bfr[j] = *(const frag_ab*)&Bl[buf][(j*16 + fr)*LSTR + kg*8];
    #pragma unroll
    for(int i=0;i<2;i++)
      #pragma unroll
      for(int j=0;j<4;j++)
        acc[i][j] = __builtin_amdgcn_mfma_f32_16x16x32_bf16(af[i], bfr[j], acc[i][j], 0, 0, 0);
    __syncthreads();
  }

  #pragma unroll
  for(int i=0;i<2;i++){
    int crow = row0 + w*32 + i*16 + kg*4;
    #pragma unroll
    for(int j=0;j<4;j++){
      int ccol = j*16 + fr;
      #pragma unroll
      for(int r=0;r<4;r++){
        if(crow + r < M) Out8[(size_t)(crow+r)*HDIM + ccol] = f2fp8(acc[i][j][r]);
      }
    }
  }
  att_epi8(acc, row0 + w*32, fr, kg, asv, adv, as_o, ad_o, gml, w, M);
  __syncthreads();
  if(t < 8){
    float v = fmaxf(fmaxf(gml[0][t], gml[1][t]), fmaxf(gml[2][t], gml[3][t]));
    atomicMax(&gmax[t], fkey(v));
  }
  #undef STAGE
}

// ---------------- bf16 MFMA GEMM (layers 2,3) with fused att ----------------
// HEADS=8: output fp8 (stride HDIM bytes); HEADS=1: output bf16 (stride OST shorts)
template<int K, int C, int OST, int HEADS>
__global__ __launch_bounds__(256) void k_gemmb(const unsigned short* __restrict__ A,
                                               const unsigned short* __restrict__ Wt,
                                               const float* __restrict__ asv, const float* __restrict__ adv,
                                               void* __restrict__ Outv,
                                               void* __restrict__ as_o, float* __restrict__ ad_o,
                                               unsigned* __restrict__ gmax, int M){
  constexpr int CT = (C + 15)/16;
  __shared__ __attribute__((aligned(16))) unsigned short Al[2][BM*LSTR];
  __shared__ __attribute__((aligned(16))) unsigned short Bl[2][64*LSTR];
  __shared__ float gml[4][8];
  int t = threadIdx.x;
  int w = t >> 6, l = t & 63;
  int row0 = blockIdx.x * BM;

  int srow = t >> 1;
  int shalf = t & 1;
  int bn = t >> 2;
  int bseg = t & 3;
  int fr = l & 15, kg = l >> 4;

  frag_cd acc[2][CT];
  #pragma unroll
  for(int i=0;i<2;i++)
    #pragma unroll
    for(int j=0;j<CT;j++) acc[i][j] = (frag_cd){0.f,0.f,0.f,0.f};

  int rg = row0 + srow; if(rg >= M) rg = M-1;
  const unsigned short* aprow = &A[(size_t)rg*K + shalf*16];

  #define STAGEB(buf, kc) do { \
    *(uint4*)&Al[buf][srow*LSTR + shalf*16]     = *(const uint4*)(aprow + (kc)); \
    *(uint4*)&Al[buf][srow*LSTR + shalf*16 + 8] = *(const uint4*)(aprow + (kc) + 8); \
    *(uint4*)&Bl[buf][bn*LSTR + bseg*8] = *(const uint4*)&Wt[bn*K + (kc) + bseg*8]; \
  } while(0)

  STAGEB(0, 0);
  __syncthreads();

  #pragma unroll 1
  for(int step = 0; step < K/BK; ++step){
    int buf = step & 1;
    if(step + 1 < K/BK) STAGEB(buf^1, (step+1)*BK);
    frag_ab af[2], bfr[CT];
    #pragma unroll
    for(int i=0;i<2;i++) af[i] = *(const frag_ab*)&Al[buf][(w*32 + i*16 + fr)*LSTR + kg*8];
    #pragma unroll
    for(int j=0;j<CT;j++) bfr[j] = *(const frag_ab*)&Bl[buf][(j*16 + fr)*LSTR + kg*8];
    #pragma unroll
    for(int i=0;i<2;i++)
      #pragma unroll
      for(int j=0;j<CT;j++)
        acc[i][j] = __builtin_amdgcn_mfma_f32_16x16x32_bf16(af[i], bfr[j], acc[i][j], 0, 0, 0);
    __syncthreads();
  }

  #pragma unroll
  for(int i=0;i<2;i++){
    int crow = row0 + w*32 + i*16 + kg*4;
    #pragma unroll
    for(int j=0;j<CT;j++){
      int ccol = j*16 + fr;
      if(ccol >= C) continue;
      #pragma unroll
      for(int r=0;r<4;r++){
        if(crow + r < M){
          if(HEADS == 8) ((unsigned char*)Outv)[(size_t)(crow+r)*HDIM + ccol] = f2fp8(acc[i][j][r]);
          else           ((unsigned short*)Outv)[(size_t)(crow+r)*OST + ccol] = f2bf(acc[i][j][r]);
        }
      }
    }
  }
  if(HEADS == 8){
    att_epi8(acc, row0 + w*32, fr, kg, asv, adv, (unsigned short*)as_o, ad_o, gml, w, M);
    __syncthreads();
    if(t < 8){
      float v = fmaxf(fmaxf(gml[0][t], gml[1][t]), fmaxf(gml[2][t], gml[3][t]));
      atomicMax(&gmax[t], fkey(v));
    }
  } else {
    att_epi1(acc, row0 + w*32, fr, kg, asv, adv, (float*)as_o, ad_o, gml, w, l, M);
    __syncthreads();
    if(t == 0){
      float v = fmaxf(fmaxf(gml[0][0], gml[1][0]), fmaxf(gml[2][0], gml[3][0]));
      atomicMax(&gmax[0], fkey(v));
    }
  }
  #undef STAGEB
}

// ---------------- aggregation, HEADS=8: fixed-max softmax, fp8 h gathers ----------------
template<bool DO_ELU>
__global__ __launch_bounds__(256) void k_agg8(const unsigned char* __restrict__ h8, const int* __restrict__ rp,
                      const int* __restrict__ col,
                      const unsigned short* __restrict__ asb, const float* __restrict__ ad_,
                      const unsigned* __restrict__ gmax,
                      const float* __restrict__ bias, unsigned short* __restrict__ out){
  int gid = blockIdx.x*256 + threadIdx.x;
  int node = gid >> 6, lane = gid & 63;
  if(node >= NN) return;
  int el = lane >> 3;
  int fl = lane & 7;
  int px = ((fl&1)<<2) | (fl>>1);          // storage position of head fl
  int beg = rp[node], end = rp[node+1];
  int deg = end - beg;
  float adn = ad_[node*8 + px];
  float M = funkey(gmax[px]) + adn;
  M = fmaxf(M, 0.2f*M);                    // leaky(gmax+ad) >= all edge logits
  float s = 0.f;
  float a[8] = {0.f,0.f,0.f,0.f,0.f,0.f,0.f,0.f};

  for(int base = 0; base < deg; base += 64){
    int cnt = deg - base; if(cnt > 64) cnt = 64;
    int idx = 0;
    if(lane < cnt) idx = col[beg + base + lane];
    int jf = cnt & ~7;
    int j = 0;
    for(; j < jf; j += 8){
      int sn = __shfl(idx, j + el);
      float ea = bf2f(asb[sn*8 + px]);
      uint2 h = *(const uint2*)&h8[(size_t)sn*HDIM + fl*8];
      float e = ea + adn; e = fmaxf(e, 0.2f*e);
      float p = exp2f(e - M);
      s += p;
      float2v q0 = __builtin_amdgcn_cvt_pk_f32_fp8(h.x, false);
      float2v q1 = __builtin_amdgcn_cvt_pk_f32_fp8(h.x, true);
      float2v q2 = __builtin_amdgcn_cvt_pk_f32_fp8(h.y, false);
      float2v q3 = __builtin_amdgcn_cvt_pk_f32_fp8(h.y, true);
      a[0] = fmaf(p, q0.x, a[0]); a[1] = fmaf(p, q0.y, a[1]);
      a[2] = fmaf(p, q1.x, a[2]); a[3] = fmaf(p, q1.y, a[3]);
      a[4] = fmaf(p, q2.x, a[4]); a[5] = fmaf(p, q2.y, a[5]);
      a[6] = fmaf(p, q3.x, a[6]); a[7] = fmaf(p, q3.y, a[7]);
    }
    if(j < cnt){
      int sn = __shfl(idx, j + el);
      float ea = bf2f(asb[sn*8 + px]);
      uint2 h = *(const uint2*)&h8[(size_t)sn*HDIM + fl*8];
      float e = ea + adn; e = fmaxf(e, 0.2f*e);
      float p = (j + el < cnt) ? exp2f(e - M) : 0.f;
      s += p;
      float2v q0 = __builtin_amdgcn_cvt_pk_f32_fp8(h.x, false);
      float2v q1 = __builtin_amdgcn_cvt_pk_f32_fp8(h.x, true);
      float2v q2 = __builtin_amdgcn_cvt_pk_f32_fp8(h.y, false);
      float2v q3 = __builtin_amdgcn_cvt_pk_f32_fp8(h.y, true);
      a[0] = fmaf(p, q0.x, a[0]); a[1] = fmaf(p, q0.y, a[1]);
      a[2] = fmaf(p, q1.x, a[2]); a[3] = fmaf(p, q1.y, a[3]);
      a[4] = fmaf(p, q2.x, a[4]); a[5] = fmaf(p, q2.y, a[5]);
      a[6] = fmaf(p, q3.x, a[6]); a[7] = fmaf(p, q3.y, a[7]);
    }
  }

  #pragma unroll
  for(int wd=8; wd<=32; wd<<=1){
    s += __shfl_xor(s, wd);
    #pragma unroll
    for(int i=0;i<8;i++) a[i] += __shfl_xor(a[i], wd);
  }

  if(el == 0){
    float inv = 1.f/s;
    float4 b0 = *(const float4*)&bias[fl*8];
    float4 b1 = *(const float4*)&bias[fl*8 + 4];
    float o[8];
    o[0]=a[0]*inv+b0.x; o[1]=a[1]*inv+b0.y; o[2]=a[2]*inv+b0.z; o[3]=a[3]*inv+b0.w;
    o[4]=a[4]*inv+b1.x; o[5]=a[5]*inv+b1.y; o[6]=a[6]*inv+b1.z; o[7]=a[7]*inv+b1.w;
    if(DO_ELU){
      #pragma unroll
      for(int i=0;i<8;i++) o[i] = (o[i] > 0.f) ? o[i] : expm1f(o[i]);
    }
    uint4 pk;
    CVTPK(pk.x, o[0], o[1]); CVTPK(pk.y, o[2], o[3]);
    CVTPK(pk.z, o[4], o[5]); CVTPK(pk.w, o[6], o[7]);
    *(uint4*)&out[(size_t)node*HDIM + fl*8] = pk;
  }
}

// ---------------- aggregation, HEADS=1 (layer 3, bf16 padded rows) + log-softmax ----------------
__global__ __launch_bounds__(256) void k_agg1(const unsigned short* __restrict__ hbf, const int* __restrict__ rp,
                      const int* __restrict__ col,
                      const float* __restrict__ as_, const float* __restrict__ ad_,
                      const unsigned* __restrict__ gmax,
                      const float* __restrict__ bias, float* __restrict__ out){
  int gid = blockIdx.x*256 + threadIdx.x;
  int node = gid >> 6, lane = gid & 63;
  if(node >= NN) return;
  int el = lane >> 3;
  int fl = lane & 7;
  bool act = fl < 5;                      // 5*8 = 40 features
  int f0 = act ? fl*8 : 0;
  int beg = rp[node], end = rp[node+1];
  int deg = end - beg;
  float adn = ad_[node];
  float M = funkey(gmax[0]) + adn;
  M = fmaxf(M, 0.2f*M);
  float s = 0.f;
  float a[8] = {0.f,0.f,0.f,0.f,0.f,0.f,0.f,0.f};

  for(int base = 0; base < deg; base += 64){
    int cnt = deg - base; if(cnt > 64) cnt = 64;
    int idx = 0;
    if(lane < cnt) idx = col[beg + base + lane];
    for(int j = 0; j < cnt; j += 8){
      int sn = __shfl(idx, j + el);
      float ea = as_[sn];
      uint4 h = *(const uint4*)&hbf[(size_t)sn*OST3 + f0];
      float e = ea + adn; e = fmaxf(e, 0.2f*e);
      float p = (j + el < cnt) ? exp2f(e - M) : 0.f;
      s += p;
      a[0] = fmaf(p, bflo(h.x), a[0]); a[1] = fmaf(p, bfhi(h.x), a[1]);
      a[2] = fmaf(p, bflo(h.y), a[2]); a[3] = fmaf(p, bfhi(h.y), a[3]);
      a[4] = fmaf(p, bflo(h.z), a[4]); a[5] = fmaf(p, bfhi(h.z), a[5]);
      a[6] = fmaf(p, bflo(h.w), a[6]); a[7] = fmaf(p, bfhi(h.w), a[7]);
    }
  }

  #pragma unroll
  for(int wd=8; wd<=32; wd<<=1){
    s += __shfl_xor(s, wd);
    #pragma unroll
    for(int i=0;i<8;i++) a[i] += __shfl_xor(a[i], wd);
  }

  float inv = 1.f/s;
  float o[8];
  #pragma unroll
  for(int i=0;i<8;i++) o[i] = a[i]*inv + (act ? bias[f0+i] : 0.f);

  float vmax = act ? fmaxf(fmaxf(fmaxf(o[0],o[1]),fmaxf(o[2],o[3])),
                           fmaxf(fmaxf(o[4],o[5]),fmaxf(o[6],o[7]))) : -INFINITY;
  #pragma unroll
  for(int wd=1; wd<8; wd<<=1) vmax = fmaxf(vmax, __shfl_xor(vmax, wd));
  float ex = 0.f;
  if(act){
    #pragma unroll
    for(int i=0;i<8;i++) ex += expf(o[i] - vmax);
  }
  #pragma unroll
  for(int wd=1; wd<8; wd<<=1) ex += __shfl_xor(ex, wd);
  float lg = logf(ex);
  if(el == 0 && act){
    float4 r0, r1;
    r0.x=o[0]-vmax-lg; r0.y=o[1]-vmax-lg; r0.z=o[2]-vmax-lg; r0.w=o[3]-vmax-lg;
    r1.x=o[4]-vmax-lg; r1.y=o[5]-vmax-lg; r1.z=o[6]-vmax-lg; r1.w=o[7]-vmax-lg;
    *(float4*)&out[(size_t)node*NCLS + f0]     = r0;
    *(float4*)&out[(size_t)node*NCLS + f0 + 4] = r1;
  }
}

// ---------------- launch ----------------
static inline size_t alignup(size_t x){ return (x + 255) & ~(size_t)255; }

extern "C" void kernel_launch(void* const* d_in, const int* in_sizes, int n_in,
                              void* d_out, int out_size, void* d_ws, size_t ws_size,
                              hipStream_t stream){
  const float* x      = (const float*)d_in[0];
  const int*   ei     = (const int*)d_in[1];
  const float* W1     = (const float*)d_in[2];
  const float* asrc1  = (const float*)d_in[3];
  const float* adst1  = (const float*)d_in[4];
  const float* b1     = (const float*)d_in[5];
  const float* W2     = (const float*)d_in[6];
  const float* asrc2  = (const float*)d_in[7];
  const float* adst2  = (const float*)d_in[8];
  const float* b2     = (const float*)d_in[9];
  const float* W3     = (const float*)d_in[10];
  const float* asrc3  = (const float*)d_in[11];
  const float* adst3  = (const float*)d_in[12];
  const float* b3     = (const float*)d_in[13];
  const int* src = ei;
  const int* dst = ei + EE;

  char* w = (char*)d_ws;
  int* rp     = (int*)w;              w += alignup((size_t)(NN+1)*4);
  int* bcur   = (int*)w;              w += alignup((size_t)NBUK*4);   // 2048B
  unsigned* gmax = (unsigned*)w;      w += alignup(32*4);             // adjacent to bcur
  unsigned short* Wt1 = (unsigned short*)w; w += alignup((size_t)64*FIN*2);
  unsigned short* Wt2 = (unsigned short*)w; w += alignup((size_t)64*HDIM*2);
  unsigned short* Wt3 = (unsigned short*)w; w += alignup((size_t)64*HDIM*2);
  float* attv = (float*)w;            w += alignup((size_t)352*4);
  int* col    = (int*)w;              w += alignup((size_t)ET*4);
  int* pbuf   = (int*)w;              w += alignup((size_t)NBUK*CAP*4);
  unsigned char* hA8 = (unsigned char*)w; w += alignup((size_t)NN*HDIM + 256);   // fp8 gather source
  unsigned short* hBb = (unsigned short*)w; w += alignup((size_t)NN*HDIM*2 + 256); // bf16 agg out / gemm in
  unsigned short* hCb = (unsigned short*)w; w += alignup((size_t)NN*OST3*2 + 256); // bf16 layer-3 h
  unsigned short* asb = (unsigned short*)w; w += alignup((size_t)NN*8*2 + 256);
  float* as3  = (float*)w;            w += alignup((size_t)NN*4);
  float* adA  = (float*)w;            w += alignup((size_t)NN*8*4);

  dim3 blk(256);
  int gWav  = (NN*64 + 255)/256;
  int gG1   = (NN + BM - 1)/BM;   // 782

  // zero bcur + gmax in one memset (adjacent)
  hipMemsetAsync(bcur, 0, 2048 + 128, stream);
  // prep (weights + scaled att vecs)
  k_prep<<<(41312 + 255)/256, blk, 0, stream>>>(W1, W2, W3, asrc1, adst1, asrc2, adst2, asrc3, adst3,
                                                Wt1, Wt2, Wt3, attv);
  // phase 0: gemm1 first half || bucket ; phase 1: gemm1 second half || bfinal
  k_mix<0><<<G1H + GBUK, blk, 0, stream>>>(x, Wt1, attv + 0, attv + 64, hA8, asb, adA, gmax + 0,
                                           src, dst, bcur, pbuf, rp, col);
  k_mix<1><<<G1H + NBUK_USED, blk, 0, stream>>>(x, Wt1, attv + 0, attv + 64, hA8, asb, adA, gmax + 0,
                                                src, dst, bcur, pbuf, rp, col);

  // layer 1 aggregation (fp8 gathers)
  k_agg8<true><<<gWav, blk, 0, stream>>>(hA8, rp, col, asb, adA, gmax + 0, b1, hBb);

  // layer 2 (gemm writes fp8 gather source)
  k_gemmb<HDIM, HDIM, HDIM, 8><<<gG1, blk, 0, stream>>>(hBb, Wt2, attv + 128, attv + 192, hA8, asb, adA, gmax + 8, NN);
  k_agg8<true><<<gWav, blk, 0, stream>>>(hA8, rp, col, asb, adA, gmax + 8, b2, hBb);

  // layer 3 (bf16 padded h rows; output precision protected)
  k_gemmb<HDIM, NCLS, OST3, 1><<<gG1, blk, 0, stream>>>(hBb, Wt3, attv + 256, attv + 304, hCb, as3, adA, gmax + 16, NN);
  k_agg1<<<gWav, blk, 0, stream>>>(hCb, rp, col, as3, adA, gmax + 16, b3, (float*)d_out);
}